// Round 6
// baseline (164.196 us; speedup 1.0000x reference)
//
#include <hip/hip_runtime.h>

#define BSZN 8
#define TT 4096
#define DIN 512
#define PP 256
#define HHH 256
#define DOUT 512
#define LCH 32              // scan chunk length == row tile
#define NCH (TT / LCH)      // 128 chunks per batch
#define NBLK (BSZN * NCH)   // 1024 blocks -> 4/CU co-resident, 16 waves/CU
#define XPS 264             // xs/xp/hsL row stride (bf16 elems), 528 B

typedef __attribute__((ext_vector_type(8))) short bf16x8;
typedef __attribute__((ext_vector_type(4))) float f32x4;

static __device__ __forceinline__ unsigned short f2bf(float x) {
  union { float f; unsigned u; } t{x};
  unsigned r = t.u + 0x7fffu + ((t.u >> 16) & 1u);  // RNE
  return (unsigned short)(r >> 16);
}

// Tiled-rotated weight layouts (k-major 32-elem tiles, 64 B rows, 16 B slot
// rotated by (row>>1)). A wave's bf16x8 fragment read of rows [r0,r0+16)
// covers EXACTLY the contiguous 1 KB [r0*64, r0*64+1024) -> direct per-lane
// global reads are single-burst coalesced; no LDS staging of weights.
// pos = tile*(NROWS*32) + row*32 + (((k>>3)&3 + (row>>1))&3)*8 + (k&7)

// ---------------------------------------------------------------------------
// Prep: PURE ELEMENTWISE. Grid = 384:
//   0-127: Wi->Wi_t  128-191: B->B_t  192-255: C->C_t  256-383: Wo->Wo_t
// ---------------------------------------------------------------------------
__global__ __launch_bounds__(256) void prep_k(
    const float* __restrict__ Wi, const float* __restrict__ Wo,
    const float* __restrict__ Cm, const float* __restrict__ Bm,
    unsigned short* __restrict__ Wi_t, unsigned short* __restrict__ B_t,
    unsigned short* __restrict__ C_t, unsigned short* __restrict__ Wo_t) {
  const int b = blockIdx.x, tid = threadIdx.x;
  if (b < 128) {                       // Wi (256x512): rows=p, k=d
    const int idx = b * 1024 + tid * 4;
    const int row = idx >> 9, d = idx & 511;
    const float4 v = *(const float4*)(Wi + idx);
    uint2 w;
    w.x = (unsigned)f2bf(v.x) | ((unsigned)f2bf(v.y) << 16);
    w.y = (unsigned)f2bf(v.z) | ((unsigned)f2bf(v.w) << 16);
    const int tile = d >> 5, kc = (d >> 3) & 3, s = (kc + (row >> 1)) & 3;
    *(uint2*)(Wi_t + tile * 8192 + row * 32 + s * 8 + (d & 7)) = w;
  } else if (b < 192) {                // B^T (rows=h, k=p): coalesced reads
    const int f = (b - 128) * 256 + tid;
    const int p = f >> 6, h = (f & 63) * 4;
    const float4 v = *(const float4*)(Bm + (size_t)p * HHH + h);
    const float vv[4] = {v.x, v.y, v.z, v.w};
    const int tile = p >> 5, kc = (p >> 3) & 3;
#pragma unroll
    for (int j = 0; j < 4; ++j) {
      const int row = h + j, s = (kc + (row >> 1)) & 3;
      B_t[tile * 8192 + row * 32 + s * 8 + (p & 7)] = f2bf(vv[j]);
    }
  } else if (b < 256) {                // C^T (rows=p, k=h): coalesced reads
    const int f = (b - 192) * 256 + tid;
    const int h = f >> 6, p = (f & 63) * 4;
    const float4 v = *(const float4*)(Cm + (size_t)h * PP + p);
    const float vv[4] = {v.x, v.y, v.z, v.w};
    const int tile = h >> 5, kc = (h >> 3) & 3;
#pragma unroll
    for (int j = 0; j < 4; ++j) {
      const int row = p + j, s = (kc + (row >> 1)) & 3;
      C_t[tile * 8192 + row * 32 + s * 8 + (h & 7)] = f2bf(vv[j]);
    }
  } else {                             // Wo (512x256): rows=o, k=p
    const int idx = (b - 256) * 1024 + tid * 4;
    const int o = idx >> 8, p = idx & 255;
    const float4 v = *(const float4*)(Wo + idx);
    uint2 w;
    w.x = (unsigned)f2bf(v.x) | ((unsigned)f2bf(v.y) << 16);
    w.y = (unsigned)f2bf(v.z) | ((unsigned)f2bf(v.w) << 16);
    const int tile = p >> 5, kc = (p >> 3) & 3, s = (kc + (o >> 1)) & 3;
    *(uint2*)(Wo_t + tile * 16384 + o * 32 + s * 8 + (p & 7)) = w;
  }
}

// ---------------------------------------------------------------------------
// Kernel A: phases 1/1.5/2/3 for a 32-row chunk. 1024 blocks, 4/CU.
// x staged in two K-halves into a 16.9 KB buffer aliased with xp; weight
// fragments read directly from L2 (coalesced). hs0 stored packed bf16.
// ---------------------------------------------------------------------------
__global__ __launch_bounds__(256, 4) void s4_scan(
    const float* __restrict__ x, const float* __restrict__ a,
    const unsigned short* __restrict__ Wi_t, const float* __restrict__ bi,
    const unsigned short* __restrict__ B_t, unsigned int* __restrict__ hs0_g,
    float* __restrict__ carry_g) {
  __shared__ alignas(16) char smem[16896];      // [32][264] bf16
  unsigned short* xs = (unsigned short*)smem;   // x half-tile
  unsigned short* xp = (unsigned short*)smem;   // alias (after phase 1)

  const int tid = threadIdx.x, wave = tid >> 6, lane = tid & 63;
  const int l15 = lane & 15, q = lane >> 4;
  const int bc = blockIdx.x;
  const size_t row0 = (size_t)bc * LCH;
  const int wc = wave * 64;

  int wrot[4];                // [256-row] k32 tile frag offsets (bytes)
#pragma unroll
  for (int ni = 0; ni < 4; ++ni) {
    const int r = wc + ni * 16 + l15;
    wrot[ni] = r * 64 + (((q + (r >> 1)) & 3) << 4);
  }
  int xpb[2];                 // xs/xp frag row offsets
#pragma unroll
  for (int mi = 0; mi < 2; ++mi) xpb[mi] = (mi * 16 + l15) * XPS + q * 8;

  // ---- phase 1: xW = x @ Wi^T (32x256), two K-halves ----
  f32x4 acc[2][4];
#pragma unroll
  for (int i = 0; i < 2; ++i)
#pragma unroll
    for (int j = 0; j < 4; ++j) acc[i][j] = f32x4{0.f, 0.f, 0.f, 0.f};

  for (int hh = 0; hh < 2; ++hh) {
    {  // stage 32x256 f32 -> bf16 (8 float4 per thread)
      float4 xv[8];
#pragma unroll
      for (int i = 0; i < 8; ++i) {
        const int f = i * 256 + tid;
        xv[i] = *(const float4*)(x + (row0 + (f >> 6)) * DIN + hh * 256 +
                                 (f & 63) * 4);
      }
#pragma unroll
      for (int i = 0; i < 8; ++i) {
        const int f = i * 256 + tid;
        uint2 w;
        w.x = (unsigned)f2bf(xv[i].x) | ((unsigned)f2bf(xv[i].y) << 16);
        w.y = (unsigned)f2bf(xv[i].z) | ((unsigned)f2bf(xv[i].w) << 16);
        *(uint2*)(xs + (f >> 6) * XPS + (f & 63) * 4) = w;
      }
    }
    __syncthreads();
    const char* WiB = (const char*)Wi_t + hh * 8 * 16384;
    for (int t = 0; t < 4; ++t) {  // K-step 64 within half
      bf16x8 af[2][2], bfv[4][2];
#pragma unroll
      for (int mi = 0; mi < 2; ++mi) {
        af[mi][0] = *(const bf16x8*)(xs + xpb[mi] + t * 64);
        af[mi][1] = *(const bf16x8*)(xs + xpb[mi] + t * 64 + 32);
      }
#pragma unroll
      for (int ni = 0; ni < 4; ++ni) {
        bfv[ni][0] = *(const bf16x8*)(WiB + (t * 2) * 16384 + wrot[ni]);
        bfv[ni][1] = *(const bf16x8*)(WiB + (t * 2 + 1) * 16384 + wrot[ni]);
      }
#pragma unroll
      for (int kk = 0; kk < 2; ++kk)
#pragma unroll
        for (int mi = 0; mi < 2; ++mi)
#pragma unroll
          for (int ni = 0; ni < 4; ++ni)
            acc[mi][ni] = __builtin_amdgcn_mfma_f32_16x16x32_bf16(
                af[mi][kk], bfv[ni][kk], acc[mi][ni], 0, 0, 0);
    }
    __syncthreads();  // done reading xs half before restaging / xp write
  }

  // ---- phase 1.5: relu+bias -> xp [32][XPS] ----
#pragma unroll
  for (int ni = 0; ni < 4; ++ni) {
    const int col = wc + ni * 16 + l15;
    const float bb = bi[col];
#pragma unroll
    for (int mi = 0; mi < 2; ++mi)
#pragma unroll
      for (int reg = 0; reg < 4; ++reg) {
        const int row = mi * 16 + q * 4 + reg;
        xp[row * XPS + col] = f2bf(fmaxf(acc[mi][ni][reg] + bb, 0.f));
      }
  }
  __syncthreads();

  // ---- phase 2: u = xp @ B, barrier-free ----
#pragma unroll
  for (int i = 0; i < 2; ++i)
#pragma unroll
    for (int j = 0; j < 4; ++j) acc[i][j] = f32x4{0.f, 0.f, 0.f, 0.f};
  {
    const char* BB = (const char*)B_t;
    for (int t = 0; t < 4; ++t) {
      bf16x8 af[2][2], bfv[4][2];
#pragma unroll
      for (int mi = 0; mi < 2; ++mi) {
        af[mi][0] = *(const bf16x8*)(xp + xpb[mi] + t * 64);
        af[mi][1] = *(const bf16x8*)(xp + xpb[mi] + t * 64 + 32);
      }
#pragma unroll
      for (int ni = 0; ni < 4; ++ni) {
        bfv[ni][0] = *(const bf16x8*)(BB + (t * 2) * 16384 + wrot[ni]);
        bfv[ni][1] = *(const bf16x8*)(BB + (t * 2 + 1) * 16384 + wrot[ni]);
      }
#pragma unroll
      for (int kk = 0; kk < 2; ++kk)
#pragma unroll
        for (int mi = 0; mi < 2; ++mi)
#pragma unroll
          for (int ni = 0; ni < 4; ++ni)
            acc[mi][ni] = __builtin_amdgcn_mfma_f32_16x16x32_bf16(
                af[mi][kk], bfv[ni][kk], acc[mi][ni], 0, 0, 0);
    }
  }

  // ---- phase 3: register scan over 32 rows (zero-init) ----
  float aC[4], Wz[4];
#pragma unroll
  for (int ni = 0; ni < 4; ++ni) aC[ni] = a[wc + ni * 16 + l15];
#pragma unroll
  for (int ni = 0; ni < 4; ++ni) {
    const float A = aC[ni];
    const float A2 = A * A, A4 = A2 * A2, A8 = A4 * A4, A16 = A8 * A8;
    const float A4q = ((q & 1) ? A4 : 1.f) * ((q & 2) ? A8 : 1.f);
    float W = 0.f;
#pragma unroll
    for (int mi = 0; mi < 2; ++mi) {
      f32x4 v = acc[mi][ni];
      v.y = fmaf(A, v.x, v.y);
      v.z = fmaf(A, v.y, v.z);
      v.w = fmaf(A, v.z, v.w);
      const float E = v.w;
      const float E0 = __shfl(E, l15, 64);
      const float E1 = __shfl(E, l15 + 16, 64);
      const float E2 = __shfl(E, l15 + 32, 64);
      const float E3 = __shfl(E, l15 + 48, 64);
      const float s1 = E0, s2 = fmaf(A4, s1, E1), s3 = fmaf(A4, s2, E2);
      const float s4 = fmaf(A4, s3, E3);
      const float Sq = (q == 0) ? 0.f : (q == 1) ? s1 : (q == 2) ? s2 : s3;
      const float sin_ = fmaf(A4q, W, Sq);
      v.x = fmaf(A, sin_, v.x);
      v.y = fmaf(A2, sin_, v.y);
      v.z = fmaf(A2 * A, sin_, v.z);
      v.w = fmaf(A4, sin_, v.w);
      acc[mi][ni] = v;
      W = fmaf(A16, W, s4);
    }
    Wz[ni] = W;
  }
  // carry (plain f32) + hs0 (packed bf16, fragment-native blocked layout)
  if (q == 0) {
#pragma unroll
    for (int ni = 0; ni < 4; ++ni)
      carry_g[(size_t)bc * HHH + wc + ni * 16 + l15] = Wz[ni];
  }
#pragma unroll
  for (int ni = 0; ni < 4; ++ni)
#pragma unroll
    for (int mi = 0; mi < 2; ++mi) {
      const f32x4 v = acc[mi][ni];
      uint2 pk;
      pk.x = (unsigned)f2bf(v.x) | ((unsigned)f2bf(v.y) << 16);
      pk.y = (unsigned)f2bf(v.z) | ((unsigned)f2bf(v.w) << 16);
      const size_t e =
          (((size_t)bc * 4 + wave) * 8 + ni * 2 + mi) * 64 + lane;
      *(uint2*)(hs0_g + e * 2) = pk;
    }
}

// ---------------------------------------------------------------------------
// Kernel B: per-batch prefix over 128 chunk carries. 8 blocks x 256 threads.
// ---------------------------------------------------------------------------
__global__ __launch_bounds__(256) void s4_prefix(
    const float* __restrict__ a, const float* __restrict__ carry_g,
    float* __restrict__ P_g) {
  const int b = blockIdx.x, t = threadIdx.x;
  float A = a[t];
#pragma unroll
  for (int j = 0; j < 5; ++j) A *= A;  // A^32
  const float* cg = carry_g + (size_t)b * NCH * HHH + t;
  float* pg = P_g + (size_t)b * NCH * HHH + t;
  float P = 0.f;
  for (int c0 = 0; c0 < NCH; c0 += 16) {
    float cv[16];
#pragma unroll
    for (int i = 0; i < 16; ++i) cv[i] = cg[(size_t)(c0 + i) * HHH];
#pragma unroll
    for (int i = 0; i < 16; ++i) {
      pg[(size_t)(c0 + i) * HHH] = P;
      P = fmaf(A, P, cv[i]);
    }
  }
}

// ---------------------------------------------------------------------------
// Kernel C: fixup + 4a (y=hs@C) + 4b (out=y@Wo^T+bo). 1024 blocks, 4/CU.
// Direct coalesced C_t/Wo_t fragment reads; 3 barriers; 4b g-split for VGPR.
// ---------------------------------------------------------------------------
__global__ __launch_bounds__(256, 4) void s4_out(
    const float* __restrict__ a, const unsigned int* __restrict__ hs0_g,
    const float* __restrict__ P_g, const unsigned short* __restrict__ C_t,
    const unsigned short* __restrict__ Wo_t, const float* __restrict__ bo,
    float* __restrict__ out) {
  __shared__ alignas(16) char smem[16896];
  unsigned short* hsL = (unsigned short*)smem;  // [32][264] bf16

  const int tid = threadIdx.x, wave = tid >> 6, lane = tid & 63;
  const int l15 = lane & 15, q = lane >> 4;
  const int bc = blockIdx.x;
  const size_t row0 = (size_t)bc * LCH;
  const int wc = wave * 64;

  int wrot[4];
#pragma unroll
  for (int ni = 0; ni < 4; ++ni) {
    const int r = wc + ni * 16 + l15;
    wrot[ni] = r * 64 + (((q + (r >> 1)) & 3) << 4);
  }
  int crot[2][4];             // [512-row] k32 tile offsets (Wo_t), bytes
#pragma unroll
  for (int g = 0; g < 2; ++g)
#pragma unroll
    for (int ni = 0; ni < 4; ++ni) {
      const int r = wave * 128 + g * 64 + ni * 16 + l15;
      crot[g][ni] = r * 64 + (((q + (r >> 1)) & 3) << 4);
    }
  int xpb[2];
#pragma unroll
  for (int mi = 0; mi < 2; ++mi) xpb[mi] = (mi * 16 + l15) * XPS + q * 8;

  // ---- load packed hs0 + fixup ----
  f32x4 acc[2][4];
#pragma unroll
  for (int ni = 0; ni < 4; ++ni)
#pragma unroll
    for (int mi = 0; mi < 2; ++mi) {
      const size_t e =
          (((size_t)bc * 4 + wave) * 8 + ni * 2 + mi) * 64 + lane;
      const uint2 pk = *(const uint2*)(hs0_g + e * 2);
      f32x4 v;
      v.x = __uint_as_float(pk.x << 16);
      v.y = __uint_as_float(pk.x & 0xffff0000u);
      v.z = __uint_as_float(pk.y << 16);
      v.w = __uint_as_float(pk.y & 0xffff0000u);
      acc[mi][ni] = v;
    }
#pragma unroll
  for (int ni = 0; ni < 4; ++ni) {
    const int col = wc + ni * 16 + l15;
    const float A = a[col];
    const float P = P_g[(size_t)bc * HHH + col];
    const float A2 = A * A, A4 = A2 * A2, A8 = A4 * A4, A16 = A8 * A8;
    const float A4q = ((q & 1) ? A4 : 1.f) * ((q & 2) ? A8 : 1.f);
    float fm = A4q * A * P;  // A^(4q+1) * P
#pragma unroll
    for (int mi = 0; mi < 2; ++mi) {
      f32x4 v = acc[mi][ni];
      v.x += fm;
      v.y = fmaf(A, fm, v.y);
      v.z = fmaf(A2, fm, v.z);
      v.w = fmaf(A2 * A, fm, v.w);
      acc[mi][ni] = v;
      fm *= A16;
    }
  }
  // hs -> hsL bf16
#pragma unroll
  for (int ni = 0; ni < 4; ++ni) {
    const int col = wc + ni * 16 + l15;
#pragma unroll
    for (int mi = 0; mi < 2; ++mi)
#pragma unroll
      for (int reg = 0; reg < 4; ++reg)
        hsL[(mi * 16 + q * 4 + reg) * XPS + col] = f2bf(acc[mi][ni][reg]);
  }
  __syncthreads();

  // ---- phase 4a: y = hs @ C (K=256), barrier-free ----
#pragma unroll
  for (int i = 0; i < 2; ++i)
#pragma unroll
    for (int j = 0; j < 4; ++j) acc[i][j] = f32x4{0.f, 0.f, 0.f, 0.f};
  {
    const char* CB = (const char*)C_t;
    for (int t = 0; t < 4; ++t) {
      bf16x8 af[2][2], bfv[4][2];
#pragma unroll
      for (int mi = 0; mi < 2; ++mi) {
        af[mi][0] = *(const bf16x8*)(hsL + xpb[mi] + t * 64);
        af[mi][1] = *(const bf16x8*)(hsL + xpb[mi] + t * 64 + 32);
      }
#pragma unroll
      for (int ni = 0; ni < 4; ++ni) {
        bfv[ni][0] = *(const bf16x8*)(CB + (t * 2) * 16384 + wrot[ni]);
        bfv[ni][1] = *(const bf16x8*)(CB + (t * 2 + 1) * 16384 + wrot[ni]);
      }
#pragma unroll
      for (int kk = 0; kk < 2; ++kk)
#pragma unroll
        for (int mi = 0; mi < 2; ++mi)
#pragma unroll
          for (int ni = 0; ni < 4; ++ni)
            acc[mi][ni] = __builtin_amdgcn_mfma_f32_16x16x32_bf16(
                af[mi][kk], bfv[ni][kk], acc[mi][ni], 0, 0, 0);
    }
  }
  __syncthreads();  // all waves done reading hsL

  // y -> hsL (no bias; bo applies after Wo)
#pragma unroll
  for (int ni = 0; ni < 4; ++ni) {
    const int col = wc + ni * 16 + l15;
#pragma unroll
    for (int mi = 0; mi < 2; ++mi)
#pragma unroll
      for (int reg = 0; reg < 4; ++reg)
        hsL[(mi * 16 + q * 4 + reg) * XPS + col] = f2bf(acc[mi][ni][reg]);
  }
  __syncthreads();

  // ---- phase 4b: out = y @ Wo^T + bo (K=256), two col-group passes ----
  const char* WoB = (const char*)Wo_t;
#pragma unroll
  for (int g = 0; g < 2; ++g) {
    f32x4 oacc[2][4];
#pragma unroll
    for (int i = 0; i < 2; ++i)
#pragma unroll
      for (int j = 0; j < 4; ++j) oacc[i][j] = f32x4{0.f, 0.f, 0.f, 0.f};
    for (int t = 0; t < 8; ++t) {  // K-step 32, [512][32] tiles (32 KB)
      bf16x8 af[2], bfv[4];
#pragma unroll
      for (int mi = 0; mi < 2; ++mi)
        af[mi] = *(const bf16x8*)(hsL + xpb[mi] + t * 32);
#pragma unroll
      for (int ni = 0; ni < 4; ++ni)
        bfv[ni] = *(const bf16x8*)(WoB + t * 32768 + crot[g][ni]);
#pragma unroll
      for (int mi = 0; mi < 2; ++mi)
#pragma unroll
        for (int ni = 0; ni < 4; ++ni)
          oacc[mi][ni] = __builtin_amdgcn_mfma_f32_16x16x32_bf16(
              af[mi], bfv[ni], oacc[mi][ni], 0, 0, 0);
    }
#pragma unroll
    for (int ni = 0; ni < 4; ++ni) {
      const int ocol = wave * 128 + g * 64 + ni * 16 + l15;
      const float bb = bo[ocol];
#pragma unroll
      for (int mi = 0; mi < 2; ++mi)
#pragma unroll
        for (int reg = 0; reg < 4; ++reg) {
          const int row = mi * 16 + q * 4 + reg;
          out[(row0 + row) * DOUT + ocol] = oacc[mi][ni][reg] + bb;
        }
    }
  }
}

// ---------------------------------------------------------------------------
extern "C" void kernel_launch(void* const* d_in, const int* in_sizes, int n_in,
                              void* d_out, int out_size, void* d_ws,
                              size_t ws_size, hipStream_t stream) {
  const float* x  = (const float*)d_in[0];
  const float* a  = (const float*)d_in[1];
  const float* Bm = (const float*)d_in[2];
  const float* Cm = (const float*)d_in[3];
  const float* Wi = (const float*)d_in[4];
  const float* bi = (const float*)d_in[5];
  const float* Wo = (const float*)d_in[6];
  const float* bo = (const float*)d_in[7];
  float* out = (float*)d_out;

  char* ws = (char*)d_ws;
  unsigned short* Wi_t = (unsigned short*)ws; ws += (size_t)PP * DIN * 2;
  unsigned short* B_t  = (unsigned short*)ws; ws += (size_t)HHH * PP * 2;
  unsigned short* C_t  = (unsigned short*)ws; ws += (size_t)HHH * PP * 2;
  unsigned short* Wo_t = (unsigned short*)ws; ws += (size_t)DOUT * PP * 2;
  float* carry_g = (float*)ws; ws += (size_t)NBLK * HHH * 4;
  float* P_g     = (float*)ws; ws += (size_t)NBLK * HHH * 4;
  unsigned int* hs0_g = (unsigned int*)ws;  // 16.8 MB packed bf16

  prep_k<<<384, 256, 0, stream>>>(Wi, Wo, Cm, Bm, Wi_t, B_t, C_t, Wo_t);
  s4_scan<<<NBLK, 256, 0, stream>>>(x, a, Wi_t, bi, B_t, hs0_g, carry_g);
  s4_prefix<<<BSZN, 256, 0, stream>>>(a, carry_g, P_g);
  s4_out<<<NBLK, 256, 0, stream>>>(a, hs0_g, P_g, C_t, Wo_t, bo, out);
}